// Round 2
// baseline (38040.320 us; speedup 1.0000x reference)
//
#include <hip/hip_runtime.h>
#include <cmath>

// ---------- high-accuracy double transcendentals (no libm tanh) ----------
__device__ __forceinline__ double dexp_(double x) {
    // e^x, |x| clamped to 64, ~1e-14 relative accuracy
    x = fmin(fmax(x, -64.0), 64.0);
    double w = x * 1.4426950408889634;     // log2(e)
    double n = rint(w);
    double u = (w - n) * 0.6931471805599453;
    double p = 1.0 + u * (1.0 + u * (0.5 + u * (1.6666666666666666e-01 +
               u * (4.1666666666666664e-02 + u * (8.3333333333333332e-03 +
               u * (1.3888888888888889e-03 + u * (1.9841269841269841e-04 +
               u * (2.4801587301587302e-05 + u * (2.7557319223985893e-06 +
               u * (2.7557319223985888e-07 + u * 2.5052108385441720e-08))))))))));
    return ldexp(p, (int)n);
}
__device__ __forceinline__ double dtanh_(double x) {
    double ax = fabs(x);
    double e = dexp_(2.0 * ax);
    double t = 1.0 - 2.0 / (e + 1.0);
    return copysign(t, x);
}
__device__ __forceinline__ double dsig_(double x) {
    return 1.0 / (1.0 + dexp_(-x));
}

// Build transposed concatenated weights (float) + fused biases (double).
__global__ __launch_bounds__(256) void prep_kernel(
    const float* __restrict__ eWih, const float* __restrict__ eWhh,
    const float* __restrict__ ebih, const float* __restrict__ ebhh,
    const float* __restrict__ dWih, const float* __restrict__ dWhh,
    const float* __restrict__ dbih, const float* __restrict__ dbhh,
    float* __restrict__ WencT, double* __restrict__ benc,
    float* __restrict__ WdecT, double* __restrict__ bdec)
{
    const int n_enc = 257 * 1024;
    const int n_dec = 513 * 1024;
    const int total = n_enc + n_dec + 2048;
    for (int idx = blockIdx.x * blockDim.x + threadIdx.x; idx < total;
         idx += gridDim.x * blockDim.x) {
        if (idx < n_enc) {
            int k = idx >> 10, r = idx & 1023;
            WencT[idx] = (k == 0) ? eWih[r] : eWhh[r * 256 + (k - 1)];
        } else if (idx < n_enc + n_dec) {
            int j = idx - n_enc;
            int k = j >> 10, r = j & 1023;
            WdecT[j] = (k < 257) ? dWih[r * 257 + k] : dWhh[r * 256 + (k - 257)];
        } else {
            int j = idx - n_enc - n_dec;
            if (j < 1024) benc[j] = (double)ebih[j] + (double)ebhh[j];
            else bdec[j - 1024] = (double)dbih[j - 1024] + (double)dbhh[j - 1024];
        }
    }
}

// Encoder LSTM step, fp64 accumulation + fp64 activations, fp32 storage.
__global__ __launch_bounds__(256) void enc_step_kernel(
    const float* __restrict__ x, const float* __restrict__ WencT,
    const double* __restrict__ benc, const float* __restrict__ h_in,
    float* __restrict__ h_out, float* __restrict__ c_st, int t)
{
    const int rg = blockIdx.x >> 3;   // 32 row-groups x 16 rows
    const int cg = blockIdx.x & 7;    // 8 ch-groups x 32 channels
    const int tid = threadIdx.x;
    const int jl = tid & 31;
    const int rp = tid >> 5;
    const int j = cg * 32 + jl;
    const int b0 = rg * 16;

    __shared__ float sh[16][260];
    __shared__ float sx[16];

    #pragma unroll
    for (int i = 0; i < 4; ++i) {
        int idx = tid + i * 256;
        int row = idx >> 6;
        int c4 = (idx & 63) * 4;
        const float4 v = *(const float4*)&h_in[(b0 + row) * 256 + c4];
        *(float4*)&sh[row][c4] = v;
    }
    if (tid < 16) sx[tid] = x[(b0 + tid) * 256 + t];
    __syncthreads();

    const int r0 = rp * 2, r1 = r0 + 1;
    double acc[2][4];
    {
        double xa = (double)sx[r0], xb = (double)sx[r1];
        #pragma unroll
        for (int g = 0; g < 4; ++g) {
            double w = (double)WencT[g * 256 + j];
            acc[0][g] = w * xa;
            acc[1][g] = w * xb;
        }
    }
    const float* Wp = WencT + 1024 + j;
    #pragma unroll 2
    for (int k = 0; k < 256; ++k) {
        double xa = (double)sh[r0][k], xb = (double)sh[r1][k];
        #pragma unroll
        for (int g = 0; g < 4; ++g) {
            double w = (double)Wp[k * 1024 + g * 256];
            acc[0][g] += w * xa;
            acc[1][g] += w * xb;
        }
    }
    double bi = benc[j], bf = benc[256 + j], bg = benc[512 + j], bo = benc[768 + j];
    #pragma unroll
    for (int r = 0; r < 2; ++r) {
        int brow = b0 + r0 + r;
        double iv = dsig_(acc[r][0] + bi);
        double fv = dsig_(acc[r][1] + bf);
        double gv = dtanh_(acc[r][2] + bg);
        double ov = dsig_(acc[r][3] + bo);
        double c = fv * (double)c_st[brow * 256 + j] + iv * gv;
        c_st[brow * 256 + j] = (float)c;
        h_out[brow * 256 + j] = (float)(ov * dtanh_(c));
    }
}

// encW1d[b][s][u] = sum_h enc_out[s][b][h] * W1[u][h]  (fp64 accum, double out)
__global__ __launch_bounds__(256) void encW1_kernel(
    const float* __restrict__ enc_out, const float* __restrict__ W1,
    double* __restrict__ encW1d)
{
    __shared__ float sa[64][260];
    __shared__ float sw[10][257];
    const int tid = threadIdx.x;
    const int m0 = blockIdx.x * 64;
    #pragma unroll
    for (int i = 0; i < 16; ++i) {
        int idx = tid + i * 256;
        int row = idx >> 6;
        int c4 = (idx & 63) * 4;
        const float4 v = *(const float4*)&enc_out[(m0 + row) * 256 + c4];
        *(float4*)&sa[row][c4] = v;
    }
    for (int i = tid; i < 2560; i += 256) sw[i >> 8][i & 255] = W1[i];
    __syncthreads();
    for (int o = tid; o < 640; o += 256) {
        int r = o / 10;
        int u = o - r * 10;
        double acc = 0.0;
        #pragma unroll 4
        for (int k = 0; k < 256; ++k)
            acc += (double)sa[r][k] * (double)sw[u][k];
        int m = m0 + r;
        int b = m & 511;
        int s = m >> 9;
        encW1d[(b * 256 + s) * 10 + u] = acc;
    }
}

// Attention step: logits in fp64, softmax/argmax/loss in fp64, di in fp32.
__global__ __launch_bounds__(256) void att_kernel(
    const double* __restrict__ encW1d, const float* __restrict__ enc_out,
    const float* __restrict__ W2, const float* __restrict__ V,
    const float* __restrict__ h_in, const int* __restrict__ y,
    float* __restrict__ di, float* __restrict__ logp_buf,
    float* __restrict__ out_pred, int t)
{
    const int b = blockIdx.x;
    const int s = threadIdx.x;
    const int wid = s >> 6, lane = s & 63;

    __shared__ float s_h[256];
    __shared__ double s_V[12];
    __shared__ double s_W2h[12];
    __shared__ double s_ld[256];
    __shared__ float s_e[256];
    __shared__ double s_red[4];
    __shared__ int s_redi[4];
    __shared__ double s_maxd, s_Zd;
    __shared__ int s_am;

    s_h[s] = h_in[b * 256 + s];
    if (s < 10) s_V[s] = (double)V[s];
    __syncthreads();

    for (int u = wid; u < 10; u += 4) {
        double p = 0.0;
        #pragma unroll
        for (int i = 0; i < 4; ++i) {
            int k = lane + i * 64;
            p += (double)W2[u * 256 + k] * (double)s_h[k];
        }
        #pragma unroll
        for (int off = 32; off >= 1; off >>= 1) p += __shfl_down(p, off, 64);
        if (lane == 0) s_W2h[u] = p;
    }
    __syncthreads();

    const double* eW = encW1d + (b * 256 + s) * 10;
    double l = 0.0;
    #pragma unroll
    for (int u = 0; u < 10; ++u) l += s_V[u] * dtanh_(eW[u] + s_W2h[u]);
    s_ld[s] = l;

    // argmax (first-index tie-break)
    {
        double v = l; int idx = s;
        #pragma unroll
        for (int off = 32; off >= 1; off >>= 1) {
            double v2 = __shfl_down(v, off, 64);
            int i2 = __shfl_down(idx, off, 64);
            if (v2 > v || (v2 == v && i2 < idx)) { v = v2; idx = i2; }
        }
        if (lane == 0) { s_red[wid] = v; s_redi[wid] = idx; }
    }
    __syncthreads();
    if (s == 0) {
        double v = s_red[0]; int idx = s_redi[0];
        #pragma unroll
        for (int w = 1; w < 4; ++w) {
            if (s_red[w] > v || (s_red[w] == v && s_redi[w] < idx)) {
                v = s_red[w]; idx = s_redi[w];
            }
        }
        s_maxd = v; s_am = idx;
    }
    __syncthreads();

    double e = dexp_(l - s_maxd);
    s_e[s] = (float)e;
    {
        double v = e;
        #pragma unroll
        for (int off = 32; off >= 1; off >>= 1) v += __shfl_down(v, off, 64);
        if (lane == 0) s_red[wid] = v;
    }
    __syncthreads();
    if (s == 0) {
        double Z = s_red[0] + s_red[1] + s_red[2] + s_red[3];
        s_Zd = Z;
        out_pred[t * 512 + b] = (float)s_am;
        int yv = y[b * 256 + t];
        logp_buf[t * 512 + b] = (float)(s_ld[yv] - s_maxd - log(Z));
    }
    __syncthreads();

    const float rcpZ = (float)(1.0 / s_Zd);
    const float* ep = enc_out + b * 256 + s;
    float acc = 0.0f;
    #pragma unroll 8
    for (int s2 = 0; s2 < 256; ++s2) acc += s_e[s2] * ep[s2 * 131072];
    di[b * 256 + s] = acc * rcpZ;
}

// Decoder LSTM step, fp64 accumulation + fp64 activations.
__global__ __launch_bounds__(256) void dec_lstm_kernel(
    const float* __restrict__ x, const int* __restrict__ y,
    const float* __restrict__ WdecT, const double* __restrict__ bdec,
    const float* __restrict__ di, const float* __restrict__ h_in,
    float* __restrict__ h_out, float* __restrict__ c_st, int t)
{
    const int rg = blockIdx.x >> 3;
    const int cg = blockIdx.x & 7;
    const int tid = threadIdx.x;
    const int jl = tid & 31;
    const int rp = tid >> 5;
    const int j = cg * 32 + jl;
    const int b0 = rg * 16;

    __shared__ float sh[16][520];   // [0..255]=di, [256]=dec_in, [260..515]=h

    #pragma unroll
    for (int i = 0; i < 4; ++i) {
        int idx = tid + i * 256;
        int row = idx >> 6;
        int c4 = (idx & 63) * 4;
        const float4 v = *(const float4*)&di[(b0 + row) * 256 + c4];
        *(float4*)&sh[row][c4] = v;
        const float4 w = *(const float4*)&h_in[(b0 + row) * 256 + c4];
        *(float4*)&sh[row][260 + c4] = w;
    }
    if (tid < 16) {
        int b = b0 + tid;
        float dv = 0.0f;
        if (t > 0) {
            int yi = y[b * 256 + (t - 1)];
            dv = x[b * 256 + yi];
        }
        sh[tid][256] = dv;
    }
    __syncthreads();

    const int r0 = rp * 2, r1 = r0 + 1;
    double acc[2][4] = {{0,0,0,0},{0,0,0,0}};
    const float* Wp = WdecT + j;
    #pragma unroll 2
    for (int k = 0; k < 256; ++k) {
        double xa = (double)sh[r0][k], xb = (double)sh[r1][k];
        #pragma unroll
        for (int g = 0; g < 4; ++g) {
            double w = (double)Wp[k * 1024 + g * 256];
            acc[0][g] += w * xa;
            acc[1][g] += w * xb;
        }
    }
    {
        double xa = (double)sh[r0][256], xb = (double)sh[r1][256];
        #pragma unroll
        for (int g = 0; g < 4; ++g) {
            double w = (double)Wp[256 * 1024 + g * 256];
            acc[0][g] += w * xa;
            acc[1][g] += w * xb;
        }
    }
    #pragma unroll 2
    for (int k = 0; k < 256; ++k) {
        double xa = (double)sh[r0][260 + k], xb = (double)sh[r1][260 + k];
        #pragma unroll
        for (int g = 0; g < 4; ++g) {
            double w = (double)Wp[(257 + k) * 1024 + g * 256];
            acc[0][g] += w * xa;
            acc[1][g] += w * xb;
        }
    }
    double bi = bdec[j], bf = bdec[256 + j], bg = bdec[512 + j], bo = bdec[768 + j];
    #pragma unroll
    for (int r = 0; r < 2; ++r) {
        int brow = b0 + r0 + r;
        double iv = dsig_(acc[r][0] + bi);
        double fv = dsig_(acc[r][1] + bf);
        double gv = dtanh_(acc[r][2] + bg);
        double ov = dsig_(acc[r][3] + bo);
        double c = fv * (double)c_st[brow * 256 + j] + iv * gv;
        c_st[brow * 256 + j] = (float)c;
        h_out[brow * 256 + j] = (float)(ov * dtanh_(c));
    }
}

__global__ __launch_bounds__(256) void loss_kernel(
    const float* __restrict__ logp_buf, float* __restrict__ out)
{
    const int tid = threadIdx.x;
    double acc = 0.0;
    for (int i = tid; i < 131072; i += 256) acc += (double)logp_buf[i];
    __shared__ double s_red[4];
    const int wid = tid >> 6, lane = tid & 63;
    #pragma unroll
    for (int off = 32; off >= 1; off >>= 1) acc += __shfl_down(acc, off, 64);
    if (lane == 0) s_red[wid] = acc;
    __syncthreads();
    if (tid == 0) {
        out[131072] = (float)(-(s_red[0] + s_red[1] + s_red[2] + s_red[3])
                              / (512.0 * 512.0));
    }
}

extern "C" void kernel_launch(void* const* d_in, const int* in_sizes, int n_in,
                              void* d_out, int out_size, void* d_ws, size_t ws_size,
                              hipStream_t stream)
{
    const float* x    = (const float*)d_in[0];
    const int*   y    = (const int*)  d_in[1];
    const float* eWih = (const float*)d_in[2];
    const float* eWhh = (const float*)d_in[3];
    const float* ebih = (const float*)d_in[4];
    const float* ebhh = (const float*)d_in[5];
    const float* dWih = (const float*)d_in[6];
    const float* dWhh = (const float*)d_in[7];
    const float* dbih = (const float*)d_in[8];
    const float* dbhh = (const float*)d_in[9];
    const float* W1   = (const float*)d_in[10];
    const float* W2   = (const float*)d_in[11];
    const float* V    = (const float*)d_in[12];

    // doubles first (alignment), then floats
    double* encW1d = (double*)d_ws;             // 1310720 doubles
    double* benc_d = encW1d + 1310720;          // 1024
    double* bdec_d = benc_d + 1024;             // 1024
    float* enc_out = (float*)(bdec_d + 1024);   // [256][512][256] = 33554432
    float* c_st    = enc_out + 33554432;        // 131072
    float* hzero   = c_st + 131072;             // 131072
    float* hd      = hzero + 131072;            // 2 x 131072
    float* dibuf   = hd + 262144;               // 131072
    float* logp    = dibuf + 131072;            // 131072
    float* WencT   = logp + 131072;             // 263168
    float* WdecT   = WencT + 263168;            // 525312

    float* out = (float*)d_out;

    hipMemsetAsync(c_st, 0, 131072 * sizeof(float), stream);
    hipMemsetAsync(hzero, 0, 131072 * sizeof(float), stream);

    prep_kernel<<<512, 256, 0, stream>>>(eWih, eWhh, ebih, ebhh,
                                         dWih, dWhh, dbih, dbhh,
                                         WencT, benc_d, WdecT, bdec_d);

    for (int t = 0; t < 256; ++t) {
        const float* hin = (t == 0) ? hzero : (enc_out + (t - 1) * 131072);
        enc_step_kernel<<<256, 256, 0, stream>>>(x, WencT, benc_d, hin,
                                                 enc_out + t * 131072, c_st, t);
    }

    encW1_kernel<<<2048, 256, 0, stream>>>(enc_out, W1, encW1d);

    const float* enc_last = enc_out + 255 * 131072;
    for (int t = 0; t < 256; ++t) {
        const float* hin = (t == 0) ? enc_last : (hd + (t & 1) * 131072);
        float* hout = hd + ((t + 1) & 1) * 131072;
        att_kernel<<<512, 256, 0, stream>>>(encW1d, enc_out, W2, V, hin, y,
                                            dibuf, logp, out, t);
        dec_lstm_kernel<<<256, 256, 0, stream>>>(x, y, WdecT, bdec_d, dibuf,
                                                 hin, hout, c_st, t);
    }

    loss_kernel<<<1, 256, 0, stream>>>(logp, out);
}

// Round 3
// 20605.872 us; speedup vs baseline: 1.8461x; 1.8461x over previous
//
#include <hip/hip_runtime.h>
#include <cmath>

// ---------- high-accuracy double transcendentals ----------
__device__ __forceinline__ double dexp_(double x) {
    x = fmin(fmax(x, -64.0), 64.0);
    double w = x * 1.4426950408889634;     // log2(e)
    double n = rint(w);
    double u = (w - n) * 0.6931471805599453;
    double p = 1.0 + u * (1.0 + u * (0.5 + u * (1.6666666666666666e-01 +
               u * (4.1666666666666664e-02 + u * (8.3333333333333332e-03 +
               u * (1.3888888888888889e-03 + u * (1.9841269841269841e-04 +
               u * (2.4801587301587302e-05 + u * (2.7557319223985893e-06 +
               u * (2.7557319223985888e-07 + u * 2.5052108385441720e-08))))))))));
    return ldexp(p, (int)n);
}
__device__ __forceinline__ double dtanh_(double x) {
    double ax = fabs(x);
    double e = dexp_(2.0 * ax);
    double t = 1.0 - 2.0 / (e + 1.0);
    return copysign(t, x);
}
__device__ __forceinline__ double dsig_(double x) {
    return 1.0 / (1.0 + dexp_(-x));
}

// Gate-interleaved transposed weights: W[k][j*4+g], fused interleaved biases bR[j*4+g].
__global__ __launch_bounds__(256) void prep_kernel(
    const float* __restrict__ eWih, const float* __restrict__ eWhh,
    const float* __restrict__ ebih, const float* __restrict__ ebhh,
    const float* __restrict__ dWih, const float* __restrict__ dWhh,
    const float* __restrict__ dbih, const float* __restrict__ dbhh,
    float* __restrict__ WencR, double* __restrict__ bencR,
    float* __restrict__ WdecR, double* __restrict__ bdecR)
{
    const int n_enc = 257 * 1024;
    const int n_dec = 513 * 1024;
    const int total = n_enc + n_dec + 2048;
    for (int idx = blockIdx.x * blockDim.x + threadIdx.x; idx < total;
         idx += gridDim.x * blockDim.x) {
        if (idx < n_enc) {
            int k = idx >> 10, c = idx & 1023;
            int j = c >> 2, g = c & 3, r = g * 256 + j;
            WencR[idx] = (k == 0) ? eWih[r] : eWhh[r * 256 + (k - 1)];
        } else if (idx < n_enc + n_dec) {
            int i2 = idx - n_enc;
            int k = i2 >> 10, c = i2 & 1023;
            int j = c >> 2, g = c & 3, r = g * 256 + j;
            WdecR[i2] = (k < 257) ? dWih[r * 257 + k] : dWhh[r * 256 + (k - 257)];
        } else {
            int c = idx - n_enc - n_dec;
            if (c < 1024) {
                int r = (c & 3) * 256 + (c >> 2);
                bencR[c] = (double)ebih[r] + (double)ebhh[r];
            } else {
                int c2 = c - 1024;
                int r = (c2 & 3) * 256 + (c2 >> 2);
                bdecR[c2] = (double)dbih[r] + (double)dbhh[r];
            }
        }
    }
}

// Encoder LSTM step. Xcat = [x_t, h(256)], K=257. fp64 accum.
// Block: 16 rows x 16 j (x4 gates). Grid: 32 rowtiles x 16 jtiles = 512.
__global__ __launch_bounds__(256) void lstm_enc_kernel(
    const float* __restrict__ x, const float* __restrict__ W,
    const double* __restrict__ bR, const float* __restrict__ h_in, long hin_str,
    float* __restrict__ h_out,   // enc_out + t*256 ; row stride 65536
    float* __restrict__ c_st, int t)
{
    __shared__ float Xs[257 * 17];
    const int tid = threadIdx.x;
    const int row = tid & 15;
    const int jt  = tid >> 4;
    const int b0  = (blockIdx.x & 31) * 16;
    const int jg  = (blockIdx.x >> 5) * 16 + jt;
    const int wid = tid >> 6, lane = tid & 63;

    #pragma unroll
    for (int rr = 0; rr < 4; ++rr) {
        int r = wid * 4 + rr;
        const float* hp = h_in + (long)(b0 + r) * hin_str;
        float4 v = *(const float4*)&hp[lane * 4];
        Xs[(1 + lane * 4 + 0) * 17 + r] = v.x;
        Xs[(1 + lane * 4 + 1) * 17 + r] = v.y;
        Xs[(1 + lane * 4 + 2) * 17 + r] = v.z;
        Xs[(1 + lane * 4 + 3) * 17 + r] = v.w;
    }
    if (tid < 16) Xs[tid] = x[(b0 + tid) * 256 + t];   // k = 0 row
    __syncthreads();

    const float* wp = W + jg * 4;
    double a0 = 0, a1 = 0, a2 = 0, a3 = 0;
    for (int k0 = 0; k0 < 256; k0 += 8) {
        float4 w[8]; float xs[8];
        #pragma unroll
        for (int i = 0; i < 8; ++i)
            w[i] = *(const float4*)&wp[(k0 + i) * 1024];
        #pragma unroll
        for (int i = 0; i < 8; ++i)
            xs[i] = Xs[(k0 + i) * 17 + row];
        #pragma unroll
        for (int i = 0; i < 8; ++i) {
            a0 += (double)w[i].x * (double)xs[i];
            a1 += (double)w[i].y * (double)xs[i];
            a2 += (double)w[i].z * (double)xs[i];
            a3 += (double)w[i].w * (double)xs[i];
        }
    }
    {   // k = 256
        float4 w = *(const float4*)&wp[256 * 1024];
        float xs = Xs[256 * 17 + row];
        a0 += (double)w.x * (double)xs;
        a1 += (double)w.y * (double)xs;
        a2 += (double)w.z * (double)xs;
        a3 += (double)w.w * (double)xs;
    }

    double bi = bR[jg * 4 + 0], bf = bR[jg * 4 + 1];
    double bg = bR[jg * 4 + 2], bo = bR[jg * 4 + 3];
    int b = b0 + row;
    double iv = dsig_(a0 + bi);
    double fv = dsig_(a1 + bf);
    double gv = dtanh_(a2 + bg);
    double ov = dsig_(a3 + bo);
    long ci = (long)b * 256 + jg;
    double c = fv * (double)c_st[ci] + iv * gv;
    c_st[ci] = (float)c;
    h_out[(long)b * 65536 + jg] = (float)(ov * dtanh_(c));
}

// encW1d[m*10+u] = sum_h enc_out[m][h] * W1[u][h]  (m = b*256+s, fp64 accum)
__global__ __launch_bounds__(256) void encW1_kernel(
    const float* __restrict__ enc_out, const float* __restrict__ W1,
    double* __restrict__ encW1d)
{
    __shared__ float sa[64][260];
    __shared__ float sw[10][257];
    const int tid = threadIdx.x;
    const int m0 = blockIdx.x * 64;
    #pragma unroll
    for (int i = 0; i < 16; ++i) {
        int idx = tid + i * 256;
        int row = idx >> 6;
        int c4 = (idx & 63) * 4;
        const float4 v = *(const float4*)&enc_out[(long)(m0 + row) * 256 + c4];
        *(float4*)&sa[row][c4] = v;
    }
    for (int i = tid; i < 2560; i += 256) sw[i >> 8][i & 255] = W1[i];
    __syncthreads();
    for (int o = tid; o < 640; o += 256) {
        int r = o / 10;
        int u = o - r * 10;
        double acc = 0.0;
        #pragma unroll 4
        for (int k = 0; k < 256; ++k)
            acc += (double)sa[r][k] * (double)sw[u][k];
        encW1d[(long)(m0 + r) * 10 + u] = acc;
    }
}

// Attention step: logits/softmax/argmax/loss fp64, di fp32 (streaming enc_out[b][s][h]).
__global__ __launch_bounds__(256) void att_kernel(
    const double* __restrict__ encW1d, const float* __restrict__ enc_out,
    const float* __restrict__ W2, const float* __restrict__ V,
    const float* __restrict__ h_in, long hin_str, const int* __restrict__ y,
    float* __restrict__ di, float* __restrict__ logp_buf,
    float* __restrict__ out_pred, int t)
{
    const int b = blockIdx.x;
    const int s = threadIdx.x;
    const int wid = s >> 6, lane = s & 63;

    __shared__ float s_h[256];
    __shared__ double s_V[12];
    __shared__ double s_W2h[12];
    __shared__ double s_ld[256];
    __shared__ float s_e[256];
    __shared__ double s_red[4];
    __shared__ int s_redi[4];
    __shared__ double s_maxd, s_Zd;
    __shared__ int s_am;

    s_h[s] = h_in[(long)b * hin_str + s];
    if (s < 10) s_V[s] = (double)V[s];
    __syncthreads();

    for (int u = wid; u < 10; u += 4) {
        double p = 0.0;
        #pragma unroll
        for (int i = 0; i < 4; ++i) {
            int k = lane + i * 64;
            p += (double)W2[u * 256 + k] * (double)s_h[k];
        }
        #pragma unroll
        for (int off = 32; off >= 1; off >>= 1) p += __shfl_down(p, off, 64);
        if (lane == 0) s_W2h[u] = p;
    }
    __syncthreads();

    const double* eW = encW1d + ((long)b * 256 + s) * 10;
    double l = 0.0;
    #pragma unroll
    for (int u = 0; u < 10; ++u) l += s_V[u] * dtanh_(eW[u] + s_W2h[u]);
    s_ld[s] = l;

    {   // argmax (first-index tie-break)
        double v = l; int idx = s;
        #pragma unroll
        for (int off = 32; off >= 1; off >>= 1) {
            double v2 = __shfl_down(v, off, 64);
            int i2 = __shfl_down(idx, off, 64);
            if (v2 > v || (v2 == v && i2 < idx)) { v = v2; idx = i2; }
        }
        if (lane == 0) { s_red[wid] = v; s_redi[wid] = idx; }
    }
    __syncthreads();
    if (s == 0) {
        double v = s_red[0]; int idx = s_redi[0];
        #pragma unroll
        for (int w = 1; w < 4; ++w) {
            if (s_red[w] > v || (s_red[w] == v && s_redi[w] < idx)) {
                v = s_red[w]; idx = s_redi[w];
            }
        }
        s_maxd = v; s_am = idx;
    }
    __syncthreads();

    double e = dexp_(l - s_maxd);
    s_e[s] = (float)e;
    {
        double v = e;
        #pragma unroll
        for (int off = 32; off >= 1; off >>= 1) v += __shfl_down(v, off, 64);
        if (lane == 0) s_red[wid] = v;
    }
    __syncthreads();
    if (s == 0) {
        double Z = s_red[0] + s_red[1] + s_red[2] + s_red[3];
        s_Zd = Z;
        out_pred[t * 512 + b] = (float)s_am;
        int yv = y[b * 256 + t];
        logp_buf[t * 512 + b] = (float)(s_ld[yv] - s_maxd - log(Z));
    }
    __syncthreads();

    const float rcpZ = (float)(1.0 / s_Zd);
    const float* ep = enc_out + (long)b * 65536 + s;
    float acc0 = 0.f, acc1 = 0.f, acc2 = 0.f, acc3 = 0.f;
    for (int s2 = 0; s2 < 256; s2 += 4) {
        acc0 += s_e[s2 + 0] * ep[(s2 + 0) * 256];
        acc1 += s_e[s2 + 1] * ep[(s2 + 1) * 256];
        acc2 += s_e[s2 + 2] * ep[(s2 + 2) * 256];
        acc3 += s_e[s2 + 3] * ep[(s2 + 3) * 256];
    }
    di[b * 256 + s] = ((acc0 + acc1) + (acc2 + acc3)) * rcpZ;
}

// Decoder LSTM step. Xcat = [di(256), dec_in, h(256)], K=513. fp64 accum.
__global__ __launch_bounds__(256) void lstm_dec_kernel(
    const float* __restrict__ x, const int* __restrict__ y,
    const float* __restrict__ W, const double* __restrict__ bR,
    const float* __restrict__ di, const float* __restrict__ h_in, long hin_str,
    float* __restrict__ h_out, float* __restrict__ c_st, int t)
{
    __shared__ float Xs[513 * 17];
    const int tid = threadIdx.x;
    const int row = tid & 15;
    const int jt  = tid >> 4;
    const int b0  = (blockIdx.x & 31) * 16;
    const int jg  = (blockIdx.x >> 5) * 16 + jt;
    const int wid = tid >> 6, lane = tid & 63;

    #pragma unroll
    for (int rr = 0; rr < 4; ++rr) {
        int r = wid * 4 + rr;
        float4 v = *(const float4*)&di[(long)(b0 + r) * 256 + lane * 4];
        Xs[(lane * 4 + 0) * 17 + r] = v.x;
        Xs[(lane * 4 + 1) * 17 + r] = v.y;
        Xs[(lane * 4 + 2) * 17 + r] = v.z;
        Xs[(lane * 4 + 3) * 17 + r] = v.w;
        const float* hp = h_in + (long)(b0 + r) * hin_str;
        float4 u = *(const float4*)&hp[lane * 4];
        Xs[(257 + lane * 4 + 0) * 17 + r] = u.x;
        Xs[(257 + lane * 4 + 1) * 17 + r] = u.y;
        Xs[(257 + lane * 4 + 2) * 17 + r] = u.z;
        Xs[(257 + lane * 4 + 3) * 17 + r] = u.w;
    }
    if (tid < 16) {
        int b = b0 + tid;
        float dv = 0.0f;
        if (t > 0) {
            int yi = y[b * 256 + (t - 1)];
            dv = x[b * 256 + yi];
        }
        Xs[256 * 17 + tid] = dv;
    }
    __syncthreads();

    const float* wp = W + jg * 4;
    double a0 = 0, a1 = 0, a2 = 0, a3 = 0;
    for (int k0 = 0; k0 < 512; k0 += 8) {
        float4 w[8]; float xs[8];
        #pragma unroll
        for (int i = 0; i < 8; ++i)
            w[i] = *(const float4*)&wp[(k0 + i) * 1024];
        #pragma unroll
        for (int i = 0; i < 8; ++i)
            xs[i] = Xs[(k0 + i) * 17 + row];
        #pragma unroll
        for (int i = 0; i < 8; ++i) {
            a0 += (double)w[i].x * (double)xs[i];
            a1 += (double)w[i].y * (double)xs[i];
            a2 += (double)w[i].z * (double)xs[i];
            a3 += (double)w[i].w * (double)xs[i];
        }
    }
    {   // k = 512
        float4 w = *(const float4*)&wp[512 * 1024];
        float xs = Xs[512 * 17 + row];
        a0 += (double)w.x * (double)xs;
        a1 += (double)w.y * (double)xs;
        a2 += (double)w.z * (double)xs;
        a3 += (double)w.w * (double)xs;
    }

    double bi = bR[jg * 4 + 0], bf = bR[jg * 4 + 1];
    double bg = bR[jg * 4 + 2], bo = bR[jg * 4 + 3];
    int b = b0 + row;
    double iv = dsig_(a0 + bi);
    double fv = dsig_(a1 + bf);
    double gv = dtanh_(a2 + bg);
    double ov = dsig_(a3 + bo);
    long ci = (long)b * 256 + jg;
    double c = fv * (double)c_st[ci] + iv * gv;
    c_st[ci] = (float)c;
    h_out[ci] = (float)(ov * dtanh_(c));
}

__global__ __launch_bounds__(256) void loss_kernel(
    const float* __restrict__ logp_buf, float* __restrict__ out)
{
    const int tid = threadIdx.x;
    double acc = 0.0;
    for (int i = tid; i < 131072; i += 256) acc += (double)logp_buf[i];
    __shared__ double s_red[4];
    const int wid = tid >> 6, lane = tid & 63;
    #pragma unroll
    for (int off = 32; off >= 1; off >>= 1) acc += __shfl_down(acc, off, 64);
    if (lane == 0) s_red[wid] = acc;
    __syncthreads();
    if (tid == 0) {
        out[131072] = (float)(-(s_red[0] + s_red[1] + s_red[2] + s_red[3])
                              / (512.0 * 512.0));
    }
}

extern "C" void kernel_launch(void* const* d_in, const int* in_sizes, int n_in,
                              void* d_out, int out_size, void* d_ws, size_t ws_size,
                              hipStream_t stream)
{
    const float* x    = (const float*)d_in[0];
    const int*   y    = (const int*)  d_in[1];
    const float* eWih = (const float*)d_in[2];
    const float* eWhh = (const float*)d_in[3];
    const float* ebih = (const float*)d_in[4];
    const float* ebhh = (const float*)d_in[5];
    const float* dWih = (const float*)d_in[6];
    const float* dWhh = (const float*)d_in[7];
    const float* dbih = (const float*)d_in[8];
    const float* dbhh = (const float*)d_in[9];
    const float* W1   = (const float*)d_in[10];
    const float* W2   = (const float*)d_in[11];
    const float* V    = (const float*)d_in[12];

    double* encW1d = (double*)d_ws;             // 1310720 doubles
    double* bencR  = encW1d + 1310720;          // 1024
    double* bdecR  = bencR + 1024;              // 1024
    float* enc_out = (float*)(bdecR + 1024);    // [512][256][256] (b,s,h)
    float* c_st    = enc_out + 33554432;        // 131072
    float* hzero   = c_st + 131072;             // 131072
    float* hd      = hzero + 131072;            // 2 x 131072
    float* dibuf   = hd + 262144;               // 131072
    float* logp    = dibuf + 131072;            // 131072
    float* WencR   = logp + 131072;             // 263168
    float* WdecR   = WencR + 263168;            // 525312

    float* out = (float*)d_out;

    hipMemsetAsync(c_st, 0, 131072 * sizeof(float), stream);
    hipMemsetAsync(hzero, 0, 131072 * sizeof(float), stream);

    prep_kernel<<<512, 256, 0, stream>>>(eWih, eWhh, ebih, ebhh,
                                         dWih, dWhh, dbih, dbhh,
                                         WencR, bencR, WdecR, bdecR);

    for (int t = 0; t < 256; ++t) {
        const float* hin; long hstr;
        if (t == 0) { hin = hzero; hstr = 256; }
        else        { hin = enc_out + (long)(t - 1) * 256; hstr = 65536; }
        lstm_enc_kernel<<<512, 256, 0, stream>>>(x, WencR, bencR, hin, hstr,
                                                 enc_out + (long)t * 256, c_st, t);
    }

    encW1_kernel<<<2048, 256, 0, stream>>>(enc_out, W1, encW1d);

    for (int t = 0; t < 256; ++t) {
        const float* hin; long hstr;
        if (t == 0) { hin = enc_out + 255 * 256; hstr = 65536; }
        else        { hin = hd + (t & 1) * 131072; hstr = 256; }
        float* hout = hd + ((t + 1) & 1) * 131072;
        att_kernel<<<512, 256, 0, stream>>>(encW1d, enc_out, W2, V, hin, hstr,
                                            y, dibuf, logp, out, t);
        lstm_dec_kernel<<<512, 256, 0, stream>>>(x, y, WdecR, bdecR, dibuf,
                                                 hin, hstr, hout, c_st, t);
    }

    loss_kernel<<<1, 256, 0, stream>>>(logp, out);
}

// Round 4
// 19733.241 us; speedup vs baseline: 1.9277x; 1.0442x over previous
//
#include <hip/hip_runtime.h>
#include <cmath>

// ---------- high-accuracy double transcendentals ----------
__device__ __forceinline__ double dexp_(double x) {
    x = fmin(fmax(x, -64.0), 64.0);
    double w = x * 1.4426950408889634;     // log2(e)
    double n = rint(w);
    double u = (w - n) * 0.6931471805599453;
    double p = 1.0 + u * (1.0 + u * (0.5 + u * (1.6666666666666666e-01 +
               u * (4.1666666666666664e-02 + u * (8.3333333333333332e-03 +
               u * (1.3888888888888889e-03 + u * (1.9841269841269841e-04 +
               u * (2.4801587301587302e-05 + u * (2.7557319223985893e-06 +
               u * (2.7557319223985888e-07 + u * 2.5052108385441720e-08))))))))));
    return ldexp(p, (int)n);
}
__device__ __forceinline__ double dtanh_(double x) {
    double ax = fabs(x);
    double e = dexp_(2.0 * ax);
    double t = 1.0 - 2.0 / (e + 1.0);
    return copysign(t, x);
}
__device__ __forceinline__ double dsig_(double x) {
    return 1.0 / (1.0 + dexp_(-x));
}

// Gate-interleaved transposed weights: W[k][j*4+g], fused interleaved biases bR[j*4+g].
__global__ __launch_bounds__(256) void prep_kernel(
    const float* __restrict__ eWih, const float* __restrict__ eWhh,
    const float* __restrict__ ebih, const float* __restrict__ ebhh,
    const float* __restrict__ dWih, const float* __restrict__ dWhh,
    const float* __restrict__ dbih, const float* __restrict__ dbhh,
    float* __restrict__ WencR, double* __restrict__ bencR,
    float* __restrict__ WdecR, double* __restrict__ bdecR)
{
    const int n_enc = 257 * 1024;
    const int n_dec = 513 * 1024;
    const int total = n_enc + n_dec + 2048;
    for (int idx = blockIdx.x * blockDim.x + threadIdx.x; idx < total;
         idx += gridDim.x * blockDim.x) {
        if (idx < n_enc) {
            int k = idx >> 10, c = idx & 1023;
            int j = c >> 2, g = c & 3, r = g * 256 + j;
            WencR[idx] = (k == 0) ? eWih[r] : eWhh[r * 256 + (k - 1)];
        } else if (idx < n_enc + n_dec) {
            int i2 = idx - n_enc;
            int k = i2 >> 10, c = i2 & 1023;
            int j = c >> 2, g = c & 3, r = g * 256 + j;
            WdecR[i2] = (k < 257) ? dWih[r * 257 + k] : dWhh[r * 256 + (k - 257)];
        } else {
            int c = idx - n_enc - n_dec;
            if (c < 1024) {
                int r = (c & 3) * 256 + (c >> 2);
                bencR[c] = (double)ebih[r] + (double)ebhh[r];
            } else {
                int c2 = c - 1024;
                int r = (c2 & 3) * 256 + (c2 >> 2);
                bdecR[c2] = (double)dbih[r] + (double)dbhh[r];
            }
        }
    }
}

// Encoder LSTM step. Blocked fp32 FMA + fp64 block-accumulate.
// Xs[row][0..255]=h, [256]=x_t (stride 260). Weight k: 0=x, 1+kh=h[kh].
__global__ __launch_bounds__(256) void lstm_enc_kernel(
    const float* __restrict__ x, const float* __restrict__ W,
    const double* __restrict__ bR, const float* __restrict__ h_in, long hin_str,
    float* __restrict__ h_out,   // row stride 65536 (enc_out[b][t][:])
    float* __restrict__ c_st, int t)
{
    __shared__ float Xs[16 * 260];
    const int tid = threadIdx.x;
    const int row = tid & 15;
    const int jt  = tid >> 4;
    const int b0  = (blockIdx.x & 31) * 16;
    const int jg  = (blockIdx.x >> 5) * 16 + jt;

    #pragma unroll
    for (int i = 0; i < 4; ++i) {
        int idx = tid + i * 256;
        int r = idx >> 6;
        int c4 = (idx & 63) * 4;
        float4 v = *(const float4*)&h_in[(long)(b0 + r) * hin_str + c4];
        *(float4*)&Xs[r * 260 + c4] = v;
    }
    if (tid < 16) Xs[tid * 260 + 256] = x[(b0 + tid) * 256 + t];
    __syncthreads();

    const float* wp = W + jg * 4;
    double A0 = 0, A1 = 0, A2 = 0, A3 = 0;
    const float* xr = &Xs[row * 260];
    for (int k0 = 0; k0 < 256; k0 += 8) {
        float4 w[8];
        #pragma unroll
        for (int i = 0; i < 8; ++i)
            w[i] = *(const float4*)&wp[(1 + k0 + i) * 1024];
        float4 xa = *(const float4*)&xr[k0];
        float4 xb = *(const float4*)&xr[k0 + 4];
        float xs[8] = {xa.x, xa.y, xa.z, xa.w, xb.x, xb.y, xb.z, xb.w};
        float s0 = 0.f, s1 = 0.f, s2 = 0.f, s3 = 0.f;
        #pragma unroll
        for (int i = 0; i < 8; ++i) {
            s0 = fmaf(w[i].x, xs[i], s0);
            s1 = fmaf(w[i].y, xs[i], s1);
            s2 = fmaf(w[i].z, xs[i], s2);
            s3 = fmaf(w[i].w, xs[i], s3);
        }
        A0 += (double)s0; A1 += (double)s1;
        A2 += (double)s2; A3 += (double)s3;
    }
    {   // k = 0 : x_t
        float4 w = *(const float4*)&wp[0];
        float xv = xr[256];
        A0 += (double)(w.x * xv); A1 += (double)(w.y * xv);
        A2 += (double)(w.z * xv); A3 += (double)(w.w * xv);
    }

    double bi = bR[jg * 4 + 0], bf = bR[jg * 4 + 1];
    double bg = bR[jg * 4 + 2], bo = bR[jg * 4 + 3];
    int b = b0 + row;
    double iv = dsig_(A0 + bi);
    double fv = dsig_(A1 + bf);
    double gv = dtanh_(A2 + bg);
    double ov = dsig_(A3 + bo);
    long ci = (long)b * 256 + jg;
    double c = fv * (double)c_st[ci] + iv * gv;
    c_st[ci] = (float)c;
    h_out[(long)b * 65536 + jg] = (float)(ov * dtanh_(c));
}

// encW1d[m*10+u] = sum_h enc_out[m][h] * W1[u][h]  (fp64 accum, one-shot)
__global__ __launch_bounds__(256) void encW1_kernel(
    const float* __restrict__ enc_out, const float* __restrict__ W1,
    double* __restrict__ encW1d)
{
    __shared__ float sa[64][260];
    __shared__ float sw[10][257];
    const int tid = threadIdx.x;
    const int m0 = blockIdx.x * 64;
    #pragma unroll
    for (int i = 0; i < 16; ++i) {
        int idx = tid + i * 256;
        int row = idx >> 6;
        int c4 = (idx & 63) * 4;
        const float4 v = *(const float4*)&enc_out[(long)(m0 + row) * 256 + c4];
        *(float4*)&sa[row][c4] = v;
    }
    for (int i = tid; i < 2560; i += 256) sw[i >> 8][i & 255] = W1[i];
    __syncthreads();
    for (int o = tid; o < 640; o += 256) {
        int r = o / 10;
        int u = o - r * 10;
        double acc = 0.0;
        #pragma unroll 4
        for (int k = 0; k < 256; ++k)
            acc += (double)sa[r][k] * (double)sw[u][k];
        encW1d[(long)(m0 + r) * 10 + u] = acc;
    }
}

// Attention step: logits/softmax/argmax/loss fp64, di fp32 (streaming enc_out[b][s][h]).
__global__ __launch_bounds__(256) void att_kernel(
    const double* __restrict__ encW1d, const float* __restrict__ enc_out,
    const float* __restrict__ W2, const float* __restrict__ V,
    const float* __restrict__ h_in, long hin_str, const int* __restrict__ y,
    float* __restrict__ di, float* __restrict__ logp_buf,
    float* __restrict__ out_pred, int t)
{
    const int b = blockIdx.x;
    const int s = threadIdx.x;
    const int wid = s >> 6, lane = s & 63;

    __shared__ float s_h[256];
    __shared__ double s_V[12];
    __shared__ double s_W2h[12];
    __shared__ double s_ld[256];
    __shared__ float s_e[256];
    __shared__ double s_red[4];
    __shared__ int s_redi[4];
    __shared__ double s_maxd, s_Zd;
    __shared__ int s_am;

    s_h[s] = h_in[(long)b * hin_str + s];
    if (s < 10) s_V[s] = (double)V[s];
    __syncthreads();

    for (int u = wid; u < 10; u += 4) {
        double p = 0.0;
        #pragma unroll
        for (int i = 0; i < 4; ++i) {
            int k = lane + i * 64;
            p += (double)W2[u * 256 + k] * (double)s_h[k];
        }
        #pragma unroll
        for (int off = 32; off >= 1; off >>= 1) p += __shfl_down(p, off, 64);
        if (lane == 0) s_W2h[u] = p;
    }
    __syncthreads();

    const double* eW = encW1d + ((long)b * 256 + s) * 10;
    double l = 0.0;
    #pragma unroll
    for (int u = 0; u < 10; ++u) l += s_V[u] * dtanh_(eW[u] + s_W2h[u]);
    s_ld[s] = l;

    {   // argmax (first-index tie-break)
        double v = l; int idx = s;
        #pragma unroll
        for (int off = 32; off >= 1; off >>= 1) {
            double v2 = __shfl_down(v, off, 64);
            int i2 = __shfl_down(idx, off, 64);
            if (v2 > v || (v2 == v && i2 < idx)) { v = v2; idx = i2; }
        }
        if (lane == 0) { s_red[wid] = v; s_redi[wid] = idx; }
    }
    __syncthreads();
    if (s == 0) {
        double v = s_red[0]; int idx = s_redi[0];
        #pragma unroll
        for (int w = 1; w < 4; ++w) {
            if (s_red[w] > v || (s_red[w] == v && s_redi[w] < idx)) {
                v = s_red[w]; idx = s_redi[w];
            }
        }
        s_maxd = v; s_am = idx;
    }
    __syncthreads();

    double e = dexp_(l - s_maxd);
    s_e[s] = (float)e;
    {
        double v = e;
        #pragma unroll
        for (int off = 32; off >= 1; off >>= 1) v += __shfl_down(v, off, 64);
        if (lane == 0) s_red[wid] = v;
    }
    __syncthreads();
    if (s == 0) {
        double Z = s_red[0] + s_red[1] + s_red[2] + s_red[3];
        s_Zd = Z;
        out_pred[t * 512 + b] = (float)s_am;
        int yv = y[b * 256 + t];
        logp_buf[t * 512 + b] = (float)(s_ld[yv] - s_maxd - log(Z));
    }
    __syncthreads();

    const float rcpZ = (float)(1.0 / s_Zd);
    const float* ep = enc_out + (long)b * 65536 + s;
    float acc0 = 0.f, acc1 = 0.f, acc2 = 0.f, acc3 = 0.f;
    for (int s2 = 0; s2 < 256; s2 += 4) {
        acc0 += s_e[s2 + 0] * ep[(s2 + 0) * 256];
        acc1 += s_e[s2 + 1] * ep[(s2 + 1) * 256];
        acc2 += s_e[s2 + 2] * ep[(s2 + 2) * 256];
        acc3 += s_e[s2 + 3] * ep[(s2 + 3) * 256];
    }
    di[b * 256 + s] = ((acc0 + acc1) + (acc2 + acc3)) * rcpZ;
}

// Decoder LSTM step. Blocked fp32 FMA + fp64 block-accumulate.
// Xs[row][0..255]=di, [256]=dec_in, [260..515]=h (stride 516).
// Weight k: 0..255=di, 256=dec_in, 257+kh=h[kh].
__global__ __launch_bounds__(256) void lstm_dec_kernel(
    const float* __restrict__ x, const int* __restrict__ y,
    const float* __restrict__ W, const double* __restrict__ bR,
    const float* __restrict__ di, const float* __restrict__ h_in, long hin_str,
    float* __restrict__ h_out, float* __restrict__ c_st, int t)
{
    __shared__ float Xs[16 * 516];
    const int tid = threadIdx.x;
    const int row = tid & 15;
    const int jt  = tid >> 4;
    const int b0  = (blockIdx.x & 31) * 16;
    const int jg  = (blockIdx.x >> 5) * 16 + jt;

    #pragma unroll
    for (int i = 0; i < 4; ++i) {
        int idx = tid + i * 256;
        int r = idx >> 6;
        int c4 = (idx & 63) * 4;
        float4 v = *(const float4*)&di[(long)(b0 + r) * 256 + c4];
        *(float4*)&Xs[r * 516 + c4] = v;
        float4 u = *(const float4*)&h_in[(long)(b0 + r) * hin_str + c4];
        *(float4*)&Xs[r * 516 + 260 + c4] = u;
    }
    if (tid < 16) {
        int b = b0 + tid;
        float dv = 0.0f;
        if (t > 0) {
            int yi = y[b * 256 + (t - 1)];
            dv = x[b * 256 + yi];
        }
        Xs[tid * 516 + 256] = dv;
    }
    __syncthreads();

    const float* wp = W + jg * 4;
    double A0 = 0, A1 = 0, A2 = 0, A3 = 0;
    const float* xr = &Xs[row * 516];

    // region 1: di (weights k=0..255)
    for (int k0 = 0; k0 < 256; k0 += 8) {
        float4 w[8];
        #pragma unroll
        for (int i = 0; i < 8; ++i)
            w[i] = *(const float4*)&wp[(k0 + i) * 1024];
        float4 xa = *(const float4*)&xr[k0];
        float4 xb = *(const float4*)&xr[k0 + 4];
        float xs[8] = {xa.x, xa.y, xa.z, xa.w, xb.x, xb.y, xb.z, xb.w};
        float s0 = 0.f, s1 = 0.f, s2 = 0.f, s3 = 0.f;
        #pragma unroll
        for (int i = 0; i < 8; ++i) {
            s0 = fmaf(w[i].x, xs[i], s0);
            s1 = fmaf(w[i].y, xs[i], s1);
            s2 = fmaf(w[i].z, xs[i], s2);
            s3 = fmaf(w[i].w, xs[i], s3);
        }
        A0 += (double)s0; A1 += (double)s1;
        A2 += (double)s2; A3 += (double)s3;
    }
    {   // k = 256 : dec_in
        float4 w = *(const float4*)&wp[256 * 1024];
        float xv = xr[256];
        A0 += (double)(w.x * xv); A1 += (double)(w.y * xv);
        A2 += (double)(w.z * xv); A3 += (double)(w.w * xv);
    }
    // region 2: h (weights k=257..512, Xs offset 260)
    for (int k0 = 0; k0 < 256; k0 += 8) {
        float4 w[8];
        #pragma unroll
        for (int i = 0; i < 8; ++i)
            w[i] = *(const float4*)&wp[(257 + k0 + i) * 1024];
        float4 xa = *(const float4*)&xr[260 + k0];
        float4 xb = *(const float4*)&xr[260 + k0 + 4];
        float xs[8] = {xa.x, xa.y, xa.z, xa.w, xb.x, xb.y, xb.z, xb.w};
        float s0 = 0.f, s1 = 0.f, s2 = 0.f, s3 = 0.f;
        #pragma unroll
        for (int i = 0; i < 8; ++i) {
            s0 = fmaf(w[i].x, xs[i], s0);
            s1 = fmaf(w[i].y, xs[i], s1);
            s2 = fmaf(w[i].z, xs[i], s2);
            s3 = fmaf(w[i].w, xs[i], s3);
        }
        A0 += (double)s0; A1 += (double)s1;
        A2 += (double)s2; A3 += (double)s3;
    }

    double bi = bR[jg * 4 + 0], bf = bR[jg * 4 + 1];
    double bg = bR[jg * 4 + 2], bo = bR[jg * 4 + 3];
    int b = b0 + row;
    double iv = dsig_(A0 + bi);
    double fv = dsig_(A1 + bf);
    double gv = dtanh_(A2 + bg);
    double ov = dsig_(A3 + bo);
    long ci = (long)b * 256 + jg;
    double c = fv * (double)c_st[ci] + iv * gv;
    c_st[ci] = (float)c;
    h_out[ci] = (float)(ov * dtanh_(c));
}

__global__ __launch_bounds__(256) void loss_kernel(
    const float* __restrict__ logp_buf, float* __restrict__ out)
{
    const int tid = threadIdx.x;
    double acc = 0.0;
    for (int i = tid; i < 131072; i += 256) acc += (double)logp_buf[i];
    __shared__ double s_red[4];
    const int wid = tid >> 6, lane = tid & 63;
    #pragma unroll
    for (int off = 32; off >= 1; off >>= 1) acc += __shfl_down(acc, off, 64);
    if (lane == 0) s_red[wid] = acc;
    __syncthreads();
    if (tid == 0) {
        out[131072] = (float)(-(s_red[0] + s_red[1] + s_red[2] + s_red[3])
                              / (512.0 * 512.0));
    }
}

extern "C" void kernel_launch(void* const* d_in, const int* in_sizes, int n_in,
                              void* d_out, int out_size, void* d_ws, size_t ws_size,
                              hipStream_t stream)
{
    const float* x    = (const float*)d_in[0];
    const int*   y    = (const int*)  d_in[1];
    const float* eWih = (const float*)d_in[2];
    const float* eWhh = (const float*)d_in[3];
    const float* ebih = (const float*)d_in[4];
    const float* ebhh = (const float*)d_in[5];
    const float* dWih = (const float*)d_in[6];
    const float* dWhh = (const float*)d_in[7];
    const float* dbih = (const float*)d_in[8];
    const float* dbhh = (const float*)d_in[9];
    const float* W1   = (const float*)d_in[10];
    const float* W2   = (const float*)d_in[11];
    const float* V    = (const float*)d_in[12];

    double* encW1d = (double*)d_ws;             // 1310720 doubles
    double* bencR  = encW1d + 1310720;          // 1024
    double* bdecR  = bencR + 1024;              // 1024
    float* enc_out = (float*)(bdecR + 1024);    // [512][256][256] (b,s,h)
    float* c_st    = enc_out + 33554432;        // 131072
    float* hzero   = c_st + 131072;             // 131072
    float* hd      = hzero + 131072;            // 2 x 131072
    float* dibuf   = hd + 262144;               // 131072
    float* logp    = dibuf + 131072;            // 131072
    float* WencR   = logp + 131072;             // 263168
    float* WdecR   = WencR + 263168;            // 525312

    float* out = (float*)d_out;

    hipMemsetAsync(c_st, 0, 131072 * sizeof(float), stream);
    hipMemsetAsync(hzero, 0, 131072 * sizeof(float), stream);

    prep_kernel<<<512, 256, 0, stream>>>(eWih, eWhh, ebih, ebhh,
                                         dWih, dWhh, dbih, dbhh,
                                         WencR, bencR, WdecR, bdecR);

    for (int t = 0; t < 256; ++t) {
        const float* hin; long hstr;
        if (t == 0) { hin = hzero; hstr = 256; }
        else        { hin = enc_out + (long)(t - 1) * 256; hstr = 65536; }
        lstm_enc_kernel<<<512, 256, 0, stream>>>(x, WencR, bencR, hin, hstr,
                                                 enc_out + (long)t * 256, c_st, t);
    }

    encW1_kernel<<<2048, 256, 0, stream>>>(enc_out, W1, encW1d);

    for (int t = 0; t < 256; ++t) {
        const float* hin; long hstr;
        if (t == 0) { hin = enc_out + 255 * 256; hstr = 65536; }
        else        { hin = hd + (t & 1) * 131072; hstr = 256; }
        float* hout = hd + ((t + 1) & 1) * 131072;
        att_kernel<<<512, 256, 0, stream>>>(encW1d, enc_out, W2, V, hin, hstr,
                                            y, dibuf, logp, out, t);
        lstm_dec_kernel<<<512, 256, 0, stream>>>(x, y, WdecR, bdecR, dibuf,
                                                 hin, hstr, hout, c_st, t);
    }

    loss_kernel<<<1, 256, 0, stream>>>(logp, out);
}